// Round 10
// baseline (2153.042 us; speedup 1.0000x reference)
//
#include <hip/hip_runtime.h>
#include <hip/hip_bf16.h>

#define NN 50000
#define NE 100000
#define D 40
#define DE 10
#define DH 128
#define DD 1600   // D*D
#define NEG 6250  // NE/16 edge-groups
#define CH 6      // BtF nt-tiles staged per chunk (6 x 4KB = 24KB LDS)

typedef __bf16 bf16;
typedef bf16 bf16x8 __attribute__((ext_vector_type(8)));
typedef float f32x4 __attribute__((ext_vector_type(4)));

// Fragment-major layouts (one 16-B chunk per lane, contiguous per wave-load):
//   rF  idx = ((eg*4 + s)*64 + lane)*8 + j  holds r[e=eg*16+(lane&15)][k=(lane>>4)*8+s*32+j]
//   BtF idx = ((nt*4 + s)*64 + lane)*8 + j  holds e2_w[k][d*40+o], j'=nt*16+(lane&15), o=j'/40, d=j'%40

__global__ __launch_bounds__(256) void k_zero(float* __restrict__ p, int n) {
    int t = blockIdx.x * 256 + threadIdx.x;
    if (t < n) p[t] = 0.f;
}

// r (fragment-major) = relu(e_feat @ e1_w + e1_b)
__global__ __launch_bounds__(256) void k_edge1(const float* __restrict__ ef,
                                               const float* __restrict__ w,
                                               const float* __restrict__ b,
                                               bf16* __restrict__ rF) {
    int t = blockIdx.x * 256 + threadIdx.x;  // NE*16 threads exact
    int lane = t & 63;
    int e = (t >> 8) * 16 + (lane & 15);
    int kbase = (lane >> 4) * 8 + ((t >> 6) & 3) * 32;
    float efr[DE];
#pragma unroll
    for (int d = 0; d < DE; ++d) efr[d] = ef[e * DE + d];
    bf16x8 ov;
#pragma unroll
    for (int j = 0; j < 8; ++j) {
        int h = kbase + j;
        float acc = b[h];
#pragma unroll
        for (int d = 0; d < DE; ++d) acc += efr[d] * w[d * DH + h];
        ov[j] = (bf16)fmaxf(acc, 0.f);
    }
    *(bf16x8*)(rF + (size_t)t * 8) = ov;
}

// BtF fragment-major from e2_w (one-time, tiny)
__global__ __launch_bounds__(256) void k_cvtB(const float* __restrict__ w,
                                              bf16* __restrict__ btf) {
    int t = blockIdx.x * 256 + threadIdx.x;  // 100*4*64 = 25600 threads exact
    int lane = t & 63;
    int jp = (t >> 8) * 16 + (lane & 15);
    int kbase = (lane >> 4) * 8 + ((t >> 6) & 3) * 32;
    int o = jp / D, d = jp % D;
    bf16x8 ov;
#pragma unroll
    for (int j = 0; j < 8; ++j) ov[j] = (bf16)w[(kbase + j) * DD + d * D + o];
    *(bf16x8*)(btf + (size_t)t * 8) = ov;
}

// biasP[j'] = e2_b[d*40+o]
__global__ __launch_bounds__(256) void k_cvtBias(const float* __restrict__ b,
                                                 float* __restrict__ bp) {
    int t = blockIdx.x * 256 + threadIdx.x;
    if (t >= DD) return;
    int o = t / D, d = t % D;
    bp[t] = b[d * D + o];
}

// out0 = relu(n_feat @ lin0_w + lin0_b)
__global__ __launch_bounds__(256) void k_lin0(const float* __restrict__ nf,
                                              const float* __restrict__ w,
                                              const float* __restrict__ b,
                                              float* __restrict__ out) {
    int t = blockIdx.x * 256 + threadIdx.x;
    if (t >= NN * D) return;
    int o = t % D, n = t / D;
    float acc = b[o];
    const float* x = nf + n * D;
#pragma unroll
    for (int d = 0; d < D; ++d) acc += x[d] * w[d * D + o];
    out[t] = fmaxf(acc, 0.f);
}

// Fully-fused per-step kernel: recompute W via MFMA (cheaper than streaming it:
// 128 FLOP/B vs chip ratio 400 FLOP/B) and aggregate messages.
// Block = 64 edges (4 waves x 1 edge-group of 16). BtF staged through LDS in
// CH-tile chunks so each block reads BtF exactly once (L2-resident).
// LDS atomicAdd into mb required: kg-lanes can collide on same (r15,o).
__global__ __launch_bounds__(256) void k_fusedAll(const float* __restrict__ x,
                                                  const bf16* __restrict__ btf,
                                                  const float* __restrict__ biasp,
                                                  const bf16* __restrict__ rF,
                                                  const int* __restrict__ src,
                                                  const int* __restrict__ dst,
                                                  float* __restrict__ agg) {
    __shared__ bf16 bts[CH * 2048];   // 24 KB
    __shared__ float xs[64][44];      // 11.3 KB, rows 16B-aligned (44%4==0)
    __shared__ float mb[4][16][41];   // 10.5 KB per-wave msg accumulators
    __shared__ int ss[64], dd[64];
    int tid = threadIdx.x, wave = tid >> 6, lane = tid & 63;
    int r15 = lane & 15, kg = lane >> 4;
    int egBase = blockIdx.x * 4;
    int eg = egBase + wave;
    bool active = (eg < NEG);
    int e0 = egBase * 16;
    if (tid < 64) {
        int e = e0 + tid;
        bool ok = e < NE;
        ss[tid] = ok ? src[e] : 0;
        dd[tid] = ok ? dst[e] : 0;
    }
    for (int i = tid; i < 4 * 16 * 41; i += 256) ((float*)mb)[i] = 0.f;
    __syncthreads();
    for (int i = tid; i < 64 * D; i += 256) {
        int e_l = i / D, o = i % D;
        if (e0 + e_l < NE) xs[e_l][o] = x[ss[e_l] * D + o];
    }
    bf16x8 b[4];
    if (active) {
#pragma unroll
        for (int s = 0; s < 4; ++s)
            b[s] = *(const bf16x8*)(rF + (size_t)((eg * 4 + s) * 64 + lane) * 8);
    }
    __syncthreads();
    for (int c = 0; c < 100; c += CH) {
        int nts = (100 - c < CH) ? (100 - c) : CH;
        for (int it = 0; it < nts; ++it) {  // stage chunk: coalesced 16B/lane
            *(bf16x8*)(bts + (size_t)(it * 256 + tid) * 8) =
                *(const bf16x8*)(btf + (size_t)((c + it) * 256 + tid) * 8);
        }
        __syncthreads();
        if (active) {
            for (int ntl = 0; ntl < nts; ++ntl) {
                int nt = c + ntl;
                f32x4 acc = {0.f, 0.f, 0.f, 0.f};
#pragma unroll
                for (int s = 0; s < 4; ++s) {
                    bf16x8 af = *(const bf16x8*)(bts + (size_t)(ntl * 2048 + s * 512 + lane * 8));
                    acc = __builtin_amdgcn_mfma_f32_16x16x32_bf16(af, b[s], acc, 0, 0, 0);
                }
                int jb = nt * 16 + kg * 4;  // 4-aligned; quad never crosses o (40%4==0)
                int o = jb / D, d0 = jb % D;
                f32x4 bias = *(const f32x4*)(biasp + jb);
                f32x4 xq = *(const f32x4*)(&xs[wave * 16 + r15][d0]);
                float p = (acc[0] + bias[0]) * xq[0] + (acc[1] + bias[1]) * xq[1] +
                          (acc[2] + bias[2]) * xq[2] + (acc[3] + bias[3]) * xq[3];
                atomicAdd(&mb[wave][r15][o], p);  // kg-lanes may collide on same (r15,o)
            }
        }
        __syncthreads();  // protect bts before next chunk's staging
    }
    if (active) {
        for (int i = lane; i < 16 * D; i += 64) {
            int e_l = i / D, o = i % D;
            atomicAdd(&agg[dd[wave * 16 + e_l] * D + o], mb[wave][e_l][o]);
        }
    }
}

// node update: m = relu(agg + out@res_w + conv_b); out' = [m,out]@msg_w + msg_b (+ n_feat if LAST)
template <int LAST>
__global__ __launch_bounds__(256) void k_node(const float* __restrict__ out,
                                              const float* __restrict__ agg,
                                              const float* __restrict__ res_w,
                                              const float* __restrict__ conv_b,
                                              const float* __restrict__ msg_w,
                                              const float* __restrict__ msg_b,
                                              const float* __restrict__ nf,
                                              float* __restrict__ out_new) {
    __shared__ float xs[6][D], ms[6][D];
    int ni = threadIdx.x / D, o = threadIdx.x % D;
    int n = blockIdx.x * 6 + ni;
    bool ok = (ni < 6) && (n < NN);
    if (ok) xs[ni][o] = out[n * D + o];
    __syncthreads();
    if (ok) {
        float t = conv_b[o] + agg[n * D + o];
#pragma unroll
        for (int d = 0; d < D; ++d) t += xs[ni][d] * res_w[d * D + o];
        ms[ni][o] = fmaxf(t, 0.f);
    }
    __syncthreads();
    if (ok) {
        float acc = msg_b[o];
#pragma unroll
        for (int d = 0; d < D; ++d)
            acc += ms[ni][d] * msg_w[d * D + o] + xs[ni][d] * msg_w[(D + d) * D + o];
        if (LAST) acc += nf[n * D + o];
        out_new[n * D + o] = acc;
    }
}

extern "C" void kernel_launch(void* const* d_in, const int* in_sizes, int n_in,
                              void* d_out, int out_size, void* d_ws, size_t ws_size,
                              hipStream_t stream) {
    const float* n_feat = (const float*)d_in[0];
    const float* e_feat = (const float*)d_in[1];
    const int* src = (const int*)d_in[2];
    const int* dst = (const int*)d_in[3];
    const float* lin0_w = (const float*)d_in[4];
    const float* lin0_b = (const float*)d_in[5];
    const float* msg_w = (const float*)d_in[6];
    const float* msg_b = (const float*)d_in[7];
    const float* e1_w = (const float*)d_in[8];
    const float* e1_b = (const float*)d_in[9];
    const float* e2_w = (const float*)d_in[10];
    const float* e2_b = (const float*)d_in[11];
    const float* res_w = (const float*)d_in[12];
    const float* conv_b = (const float*)d_in[13];
    float* outF = (float*)d_out;

    char* p = (char*)d_ws;
    bf16* rF = (bf16*)p;      p += (size_t)NE * DH * 2;   // 25.6 MB
    bf16* BtF = (bf16*)p;     p += (size_t)DD * DH * 2;   // 0.41 MB
    float* biasP = (float*)p; p += (size_t)DD * 4;        // 6.4 KB
    float* outA = (float*)p;  p += (size_t)NN * D * 4;    // 8 MB
    float* outB = (float*)p;  p += (size_t)NN * D * 4;    // 8 MB
    float* agg = (float*)p;   p += (size_t)NN * D * 4;    // 8 MB

    k_edge1<<<(NE * 16) / 256, 256, 0, stream>>>(e_feat, e1_w, e1_b, rF);
    k_cvtB<<<(100 * 4 * 64) / 256, 256, 0, stream>>>(e2_w, BtF);
    k_cvtBias<<<(DD + 255) / 256, 256, 0, stream>>>(e2_b, biasP);
    k_lin0<<<(NN * D + 255) / 256, 256, 0, stream>>>(n_feat, lin0_w, lin0_b, outA);

    float* cur = outA;
    float* nxt = outB;
    for (int s = 0; s < 6; ++s) {
        k_zero<<<(NN * D + 255) / 256, 256, 0, stream>>>(agg, NN * D);
        k_fusedAll<<<(NEG + 3) / 4, 256, 0, stream>>>(cur, BtF, biasP, rF, src, dst, agg);
        if (s == 5) {
            k_node<1><<<(NN + 5) / 6, 256, 0, stream>>>(cur, agg, res_w, conv_b,
                                                        msg_w, msg_b, n_feat, outF);
        } else {
            k_node<0><<<(NN + 5) / 6, 256, 0, stream>>>(cur, agg, res_w, conv_b,
                                                        msg_w, msg_b, n_feat, nxt);
            float* t = cur; cur = nxt; nxt = t;
        }
    }
}

// Round 13
// 1963.654 us; speedup vs baseline: 1.0964x; 1.0964x over previous
//
// Resubmission (3rd attempt) of the v2 k_msgFused kernel — Rounds 11 and 12
// both failed on container infra (UnresponsiveContainer, same dead container
// as R3/6/7/8); this source has never been compiled or benched.
#include <hip/hip_runtime.h>
#include <hip/hip_bf16.h>

#define NN 50000
#define NE 100000
#define D 40
#define DE 10
#define DH 128
#define DD 1600   // D*D
#define NEG 6250  // NE/16 edge-groups

typedef __bf16 bf16;
typedef bf16 bf16x8 __attribute__((ext_vector_type(8)));
typedef float f32x4 __attribute__((ext_vector_type(4)));

// Fragment-major layouts (one 16-B chunk per lane, contiguous per wave-load):
//   rF  idx = ((eg*4 + s)*64 + lane)*8 + j  holds r[e=eg*16+(lane&15)][k=(lane>>4)*8+s*32+j]
//   BtF idx = ((nt*4 + s)*64 + lane)*8 + j  holds e2_w[k][d*40+o], j'=nt*16+(lane&15), o=j'/40, d=j'%40

__global__ __launch_bounds__(256) void k_zero(float* __restrict__ p, int n) {
    int t = blockIdx.x * 256 + threadIdx.x;
    if (t < n) p[t] = 0.f;
}

// r (fragment-major) = relu(e_feat @ e1_w + e1_b)
__global__ __launch_bounds__(256) void k_edge1(const float* __restrict__ ef,
                                               const float* __restrict__ w,
                                               const float* __restrict__ b,
                                               bf16* __restrict__ rF) {
    int t = blockIdx.x * 256 + threadIdx.x;  // NE*16 threads exact
    int lane = t & 63;
    int e = (t >> 8) * 16 + (lane & 15);
    int kbase = (lane >> 4) * 8 + ((t >> 6) & 3) * 32;
    float efr[DE];
#pragma unroll
    for (int d = 0; d < DE; ++d) efr[d] = ef[e * DE + d];
    bf16x8 ov;
#pragma unroll
    for (int j = 0; j < 8; ++j) {
        int h = kbase + j;
        float acc = b[h];
#pragma unroll
        for (int d = 0; d < DE; ++d) acc += efr[d] * w[d * DH + h];
        ov[j] = (bf16)fmaxf(acc, 0.f);
    }
    *(bf16x8*)(rF + (size_t)t * 8) = ov;
}

// BtF fragment-major from e2_w (one-time, tiny)
__global__ __launch_bounds__(256) void k_cvtB(const float* __restrict__ w,
                                              bf16* __restrict__ btf) {
    int t = blockIdx.x * 256 + threadIdx.x;  // 100*4*64 = 25600 threads exact
    int lane = t & 63;
    int jp = (t >> 8) * 16 + (lane & 15);
    int kbase = (lane >> 4) * 8 + ((t >> 6) & 3) * 32;
    int o = jp / D, d = jp % D;
    bf16x8 ov;
#pragma unroll
    for (int j = 0; j < 8; ++j) ov[j] = (bf16)w[(kbase + j) * DD + d * D + o];
    *(bf16x8*)(btf + (size_t)t * 8) = ov;
}

// biasP[j'] = e2_b[d*40+o]
__global__ __launch_bounds__(256) void k_cvtBias(const float* __restrict__ b,
                                                 float* __restrict__ bp) {
    int t = blockIdx.x * 256 + threadIdx.x;
    if (t >= DD) return;
    int o = t / D, d = t % D;
    bp[t] = b[d * D + o];
}

// out0 = relu(n_feat @ lin0_w + lin0_b)
__global__ __launch_bounds__(256) void k_lin0(const float* __restrict__ nf,
                                              const float* __restrict__ w,
                                              const float* __restrict__ b,
                                              float* __restrict__ out) {
    int t = blockIdx.x * 256 + threadIdx.x;
    if (t >= NN * D) return;
    int o = t % D, n = t / D;
    float acc = b[o];
    const float* x = nf + n * D;
#pragma unroll
    for (int d = 0; d < D; ++d) acc += x[d] * w[d * D + o];
    out[t] = fmaxf(acc, 0.f);
}

// Fully-fused message step, v2. Per wave: 4 edge-groups (64 edges); af read
// straight from L2 (no LDS staging, no loop barriers); x held in registers as
// 5 statically-indexed f32x4 (jb = 16nt+4kg has period 5 in nt); msg accum in
// per-group LDS with atomicAdd (kg-lanes collide on same (r15,o) — Round-4).
__global__ __launch_bounds__(256) void k_msgFused(const float* __restrict__ x,
                                                  const bf16* __restrict__ btf,
                                                  const float* __restrict__ biasp,
                                                  const bf16* __restrict__ rF,
                                                  const int* __restrict__ src,
                                                  const int* __restrict__ dst,
                                                  float* __restrict__ agg) {
    __shared__ float mb[16][16][41];  // 42 KB: [group][edge-in-group][o]
    __shared__ int dd_s[16][16];
    int tid = threadIdx.x, wave = tid >> 6, lane = tid & 63;
    int r15 = lane & 15, kg = lane >> 4;
    int g0 = blockIdx.x * 16;  // first edge-group of this block

    for (int i = tid; i < 16 * 16 * 41; i += 256) ((float*)mb)[i] = 0.f;
    {
        int e = g0 * 16 + tid;
        if (e < NE) dd_s[tid >> 4][tid & 15] = dst[e];
    }

    bool act[4];
    int eg[4];
    bf16x8 b[4][4];
    f32x4 xq[4][5];
#pragma unroll
    for (int g = 0; g < 4; ++g) {
        eg[g] = g0 + wave * 4 + g;
        act[g] = eg[g] < NEG;
        if (act[g]) {
#pragma unroll
            for (int s = 0; s < 4; ++s)
                b[g][s] = *(const bf16x8*)(rF + (size_t)((eg[g] * 4 + s) * 64 + lane) * 8);
            int sv = src[eg[g] * 16 + r15];
#pragma unroll
            for (int i = 0; i < 5; ++i) {
                int d0 = (16 * i + 4 * kg) % 40;  // static per (i,kg)
                xq[g][i] = *(const f32x4*)(x + (size_t)sv * D + d0);
            }
        }
    }
    __syncthreads();  // mb zero + dd_s visible

    for (int m = 0; m < 20; ++m) {
#pragma unroll
        for (int i = 0; i < 5; ++i) {
            int nt = 5 * m + i;
            bf16x8 af[4];
#pragma unroll
            for (int s = 0; s < 4; ++s)
                af[s] = *(const bf16x8*)(btf + (size_t)((nt * 4 + s) * 64 + lane) * 8);
            f32x4 bias = *(const f32x4*)(biasp + nt * 16 + kg * 4);
            int oi = (16 * i + 4 * kg) >= 40 ? 1 : 0;  // static per (i,kg)
            int o = 2 * m + oi;
#pragma unroll
            for (int g = 0; g < 4; ++g) {
                if (act[g]) {
                    f32x4 acc = {0.f, 0.f, 0.f, 0.f};
#pragma unroll
                    for (int s = 0; s < 4; ++s)
                        acc = __builtin_amdgcn_mfma_f32_16x16x32_bf16(af[s], b[g][s], acc, 0, 0, 0);
                    f32x4 xv = xq[g][i];
                    float p = (acc[0] + bias[0]) * xv[0] + (acc[1] + bias[1]) * xv[1] +
                              (acc[2] + bias[2]) * xv[2] + (acc[3] + bias[3]) * xv[3];
                    atomicAdd(&mb[wave * 4 + g][r15][o], p);
                }
            }
        }
    }
    __syncthreads();  // drain mb atomics before flush
#pragma unroll
    for (int g = 0; g < 4; ++g) {
        if (act[g]) {
            int gl = wave * 4 + g;
            for (int i = lane; i < 16 * D; i += 64) {
                int e_l = i / D, o = i % D;
                atomicAdd(&agg[(size_t)dd_s[gl][e_l] * D + o], mb[gl][e_l][o]);
            }
        }
    }
}

// node update: m = relu(agg + out@res_w + conv_b); out' = [m,out]@msg_w + msg_b (+ n_feat if LAST)
template <int LAST>
__global__ __launch_bounds__(256) void k_node(const float* __restrict__ out,
                                              const float* __restrict__ agg,
                                              const float* __restrict__ res_w,
                                              const float* __restrict__ conv_b,
                                              const float* __restrict__ msg_w,
                                              const float* __restrict__ msg_b,
                                              const float* __restrict__ nf,
                                              float* __restrict__ out_new) {
    __shared__ float xs[6][D], ms[6][D];
    int ni = threadIdx.x / D, o = threadIdx.x % D;
    int n = blockIdx.x * 6 + ni;
    bool ok = (ni < 6) && (n < NN);
    if (ok) xs[ni][o] = out[n * D + o];
    __syncthreads();
    if (ok) {
        float t = conv_b[o] + agg[n * D + o];
#pragma unroll
        for (int d = 0; d < D; ++d) t += xs[ni][d] * res_w[d * D + o];
        ms[ni][o] = fmaxf(t, 0.f);
    }
    __syncthreads();
    if (ok) {
        float acc = msg_b[o];
#pragma unroll
        for (int d = 0; d < D; ++d)
            acc += ms[ni][d] * msg_w[d * D + o] + xs[ni][d] * msg_w[(D + d) * D + o];
        if (LAST) acc += nf[n * D + o];
        out_new[n * D + o] = acc;
    }
}

extern "C" void kernel_launch(void* const* d_in, const int* in_sizes, int n_in,
                              void* d_out, int out_size, void* d_ws, size_t ws_size,
                              hipStream_t stream) {
    const float* n_feat = (const float*)d_in[0];
    const float* e_feat = (const float*)d_in[1];
    const int* src = (const int*)d_in[2];
    const int* dst = (const int*)d_in[3];
    const float* lin0_w = (const float*)d_in[4];
    const float* lin0_b = (const float*)d_in[5];
    const float* msg_w = (const float*)d_in[6];
    const float* msg_b = (const float*)d_in[7];
    const float* e1_w = (const float*)d_in[8];
    const float* e1_b = (const float*)d_in[9];
    const float* e2_w = (const float*)d_in[10];
    const float* e2_b = (const float*)d_in[11];
    const float* res_w = (const float*)d_in[12];
    const float* conv_b = (const float*)d_in[13];
    float* outF = (float*)d_out;

    char* p = (char*)d_ws;
    bf16* rF = (bf16*)p;      p += (size_t)NE * DH * 2;   // 25.6 MB
    bf16* BtF = (bf16*)p;     p += (size_t)DD * DH * 2;   // 0.41 MB
    float* biasP = (float*)p; p += (size_t)DD * 4;        // 6.4 KB
    float* outA = (float*)p;  p += (size_t)NN * D * 4;    // 8 MB
    float* outB = (float*)p;  p += (size_t)NN * D * 4;    // 8 MB
    float* agg = (float*)p;   p += (size_t)NN * D * 4;    // 8 MB

    k_edge1<<<(NE * 16) / 256, 256, 0, stream>>>(e_feat, e1_w, e1_b, rF);
    k_cvtB<<<(100 * 4 * 64) / 256, 256, 0, stream>>>(e2_w, BtF);
    k_cvtBias<<<(DD + 255) / 256, 256, 0, stream>>>(e2_b, biasP);
    k_lin0<<<(NN * D + 255) / 256, 256, 0, stream>>>(n_feat, lin0_w, lin0_b, outA);

    float* cur = outA;
    float* nxt = outB;
    for (int s = 0; s < 6; ++s) {
        k_zero<<<(NN * D + 255) / 256, 256, 0, stream>>>(agg, NN * D);
        k_msgFused<<<(NEG + 15) / 16, 256, 0, stream>>>(cur, BtF, biasP, rF, src, dst, agg);
        if (s == 5) {
            k_node<1><<<(NN + 5) / 6, 256, 0, stream>>>(cur, agg, res_w, conv_b,
                                                        msg_w, msg_b, n_feat, outF);
        } else {
            k_node<0><<<(NN + 5) / 6, 256, 0, stream>>>(cur, agg, res_w, conv_b,
                                                        msg_w, msg_b, n_feat, nxt);
            float* t = cur; cur = nxt; nxt = t;
        }
    }
}

// Round 14
// 1783.578 us; speedup vs baseline: 1.2071x; 1.1010x over previous
//
#include <hip/hip_runtime.h>
#include <hip/hip_bf16.h>

#define NN 50000
#define NE 100000
#define D 40
#define DE 10
#define DH 128
#define DD 1600   // D*D
#define NEG 6250  // NE/16 edge-groups

typedef __bf16 bf16;
typedef bf16 bf16x8 __attribute__((ext_vector_type(8)));
typedef float f32x4 __attribute__((ext_vector_type(4)));

// Fragment-major layouts (one 16-B chunk per lane, contiguous per wave-load):
//   rF  idx = ((eg*4 + s)*64 + lane)*8 + j  holds r[e=eg*16+(lane&15)][k=(lane>>4)*8+s*32+j]
//   BtF idx = ((nt*4 + s)*64 + lane)*8 + j  holds e2_w[k][d*40+o], j'=nt*16+(lane&15), o=j'/40, d=j'%40

__global__ __launch_bounds__(256) void k_zero(float* __restrict__ p, int n) {
    int t = blockIdx.x * 256 + threadIdx.x;
    if (t < n) p[t] = 0.f;
}

// r (fragment-major) = relu(e_feat @ e1_w + e1_b)
__global__ __launch_bounds__(256) void k_edge1(const float* __restrict__ ef,
                                               const float* __restrict__ w,
                                               const float* __restrict__ b,
                                               bf16* __restrict__ rF) {
    int t = blockIdx.x * 256 + threadIdx.x;  // NE*16 threads exact
    int lane = t & 63;
    int e = (t >> 8) * 16 + (lane & 15);
    int kbase = (lane >> 4) * 8 + ((t >> 6) & 3) * 32;
    float efr[DE];
#pragma unroll
    for (int d = 0; d < DE; ++d) efr[d] = ef[e * DE + d];
    bf16x8 ov;
#pragma unroll
    for (int j = 0; j < 8; ++j) {
        int h = kbase + j;
        float acc = b[h];
#pragma unroll
        for (int d = 0; d < DE; ++d) acc += efr[d] * w[d * DH + h];
        ov[j] = (bf16)fmaxf(acc, 0.f);
    }
    *(bf16x8*)(rF + (size_t)t * 8) = ov;
}

// BtF fragment-major from e2_w (one-time, tiny)
__global__ __launch_bounds__(256) void k_cvtB(const float* __restrict__ w,
                                              bf16* __restrict__ btf) {
    int t = blockIdx.x * 256 + threadIdx.x;  // 100*4*64 = 25600 threads exact
    int lane = t & 63;
    int jp = (t >> 8) * 16 + (lane & 15);
    int kbase = (lane >> 4) * 8 + ((t >> 6) & 3) * 32;
    int o = jp / D, d = jp % D;
    bf16x8 ov;
#pragma unroll
    for (int j = 0; j < 8; ++j) ov[j] = (bf16)w[(kbase + j) * DD + d * D + o];
    *(bf16x8*)(btf + (size_t)t * 8) = ov;
}

// biasP[j'] = e2_b[d*40+o]
__global__ __launch_bounds__(256) void k_cvtBias(const float* __restrict__ b,
                                                 float* __restrict__ bp) {
    int t = blockIdx.x * 256 + threadIdx.x;
    if (t >= DD) return;
    int o = t / D, d = t % D;
    bp[t] = b[d * D + o];
}

// out0 = relu(n_feat @ lin0_w + lin0_b)
__global__ __launch_bounds__(256) void k_lin0(const float* __restrict__ nf,
                                              const float* __restrict__ w,
                                              const float* __restrict__ b,
                                              float* __restrict__ out) {
    int t = blockIdx.x * 256 + threadIdx.x;
    if (t >= NN * D) return;
    int o = t % D, n = t / D;
    float acc = b[o];
    const float* x = nf + n * D;
#pragma unroll
    for (int d = 0; d < D; ++d) acc += x[d] * w[d * D + o];
    out[t] = fmaxf(acc, 0.f);
}

// Fused message step v3. Per wave: 2 edge-groups (32 edges). No LDS at all:
// per-m register accumulators (o = 2m + oi, oi static per (i,kg)), cross-kg
// __shfl_xor reduce, direct global atomicAdd from lanes<16. af from L2 (all
// waves iterate nt in the same order -> L1/L2 reuse). VGPR ~118, 16 waves/CU.
__global__ __launch_bounds__(256, 4) void k_msgF3(const float* __restrict__ x,
                                                  const bf16* __restrict__ btf,
                                                  const float* __restrict__ biasp,
                                                  const bf16* __restrict__ rF,
                                                  const int* __restrict__ src,
                                                  const int* __restrict__ dst,
                                                  float* __restrict__ agg) {
    int tid = threadIdx.x, wave = tid >> 6, lane = tid & 63;
    int r15 = lane & 15, kg = lane >> 4;
    int eg0 = blockIdx.x * 8 + wave * 2;
    if (eg0 >= NEG) return;               // wave-uniform; no barriers in kernel
    bool act1 = (eg0 + 1) < NEG;
    int eg1 = act1 ? eg0 + 1 : eg0;       // duplicate g0 when inactive (atomics guarded)

    bf16x8 b0[4], b1[4];
#pragma unroll
    for (int s = 0; s < 4; ++s) {
        b0[s] = *(const bf16x8*)(rF + (size_t)((eg0 * 4 + s) * 64 + lane) * 8);
        b1[s] = *(const bf16x8*)(rF + (size_t)((eg1 * 4 + s) * 64 + lane) * 8);
    }
    int sv0 = src[eg0 * 16 + r15], dv0 = dst[eg0 * 16 + r15];
    int sv1 = src[eg1 * 16 + r15], dv1 = dst[eg1 * 16 + r15];
    f32x4 xq0[5], xq1[5];
#pragma unroll
    for (int i = 0; i < 5; ++i) {
        int v = 16 * i + 4 * kg;
        int d0 = v >= 40 ? v - 40 : v;    // static pattern per (i,kg)
        xq0[i] = *(const f32x4*)(x + (size_t)sv0 * D + d0);
        xq1[i] = *(const f32x4*)(x + (size_t)sv1 * D + d0);
    }

    for (int m = 0; m < 20; ++m) {
        float pe0 = 0.f, po0 = 0.f, pe1 = 0.f, po1 = 0.f;
#pragma unroll
        for (int i = 0; i < 5; ++i) {
            int nt = m * 5 + i;
            bf16x8 af[4];
#pragma unroll
            for (int s = 0; s < 4; ++s)
                af[s] = *(const bf16x8*)(btf + (size_t)((nt * 4 + s) * 64 + lane) * 8);
            f32x4 bias = *(const f32x4*)(biasp + nt * 16 + kg * 4);
            f32x4 a0 = {0.f, 0.f, 0.f, 0.f}, a1 = {0.f, 0.f, 0.f, 0.f};
#pragma unroll
            for (int s = 0; s < 4; ++s) {
                a0 = __builtin_amdgcn_mfma_f32_16x16x32_bf16(af[s], b0[s], a0, 0, 0, 0);
                a1 = __builtin_amdgcn_mfma_f32_16x16x32_bf16(af[s], b1[s], a1, 0, 0, 0);
            }
            f32x4 xv0 = xq0[i], xv1 = xq1[i];
            float p0 = (a0[0] + bias[0]) * xv0[0] + (a0[1] + bias[1]) * xv0[1] +
                       (a0[2] + bias[2]) * xv0[2] + (a0[3] + bias[3]) * xv0[3];
            float p1 = (a1[0] + bias[0]) * xv1[0] + (a1[1] + bias[1]) * xv1[1] +
                       (a1[2] + bias[2]) * xv1[2] + (a1[3] + bias[3]) * xv1[3];
            if (i <= 1) { pe0 += p0; pe1 += p1; }          // 16i+4kg < 40 always
            else if (i >= 3) { po0 += p0; po1 += p1; }     // >= 40 always
            else {                                          // i==2: kg>=2 -> hi
                bool hi = kg >= 2;
                pe0 += hi ? 0.f : p0; po0 += hi ? p0 : 0.f;
                pe1 += hi ? 0.f : p1; po1 += hi ? p1 : 0.f;
            }
        }
        // reduce partial sums across the 4 kg-lanes sharing r15
        pe0 += __shfl_xor(pe0, 16, 64); pe0 += __shfl_xor(pe0, 32, 64);
        po0 += __shfl_xor(po0, 16, 64); po0 += __shfl_xor(po0, 32, 64);
        pe1 += __shfl_xor(pe1, 16, 64); pe1 += __shfl_xor(pe1, 32, 64);
        po1 += __shfl_xor(po1, 16, 64); po1 += __shfl_xor(po1, 32, 64);
        if (lane < 16) {
            atomicAdd(&agg[(size_t)dv0 * D + 2 * m], pe0);
            atomicAdd(&agg[(size_t)dv0 * D + 2 * m + 1], po0);
            if (act1) {
                atomicAdd(&agg[(size_t)dv1 * D + 2 * m], pe1);
                atomicAdd(&agg[(size_t)dv1 * D + 2 * m + 1], po1);
            }
        }
    }
}

// node update: m = relu(agg + out@res_w + conv_b); out' = [m,out]@msg_w + msg_b (+ n_feat if LAST)
template <int LAST>
__global__ __launch_bounds__(256) void k_node(const float* __restrict__ out,
                                              const float* __restrict__ agg,
                                              const float* __restrict__ res_w,
                                              const float* __restrict__ conv_b,
                                              const float* __restrict__ msg_w,
                                              const float* __restrict__ msg_b,
                                              const float* __restrict__ nf,
                                              float* __restrict__ out_new) {
    __shared__ float xs[6][D], ms[6][D];
    int ni = threadIdx.x / D, o = threadIdx.x % D;
    int n = blockIdx.x * 6 + ni;
    bool ok = (ni < 6) && (n < NN);
    if (ok) xs[ni][o] = out[n * D + o];
    __syncthreads();
    if (ok) {
        float t = conv_b[o] + agg[n * D + o];
#pragma unroll
        for (int d = 0; d < D; ++d) t += xs[ni][d] * res_w[d * D + o];
        ms[ni][o] = fmaxf(t, 0.f);
    }
    __syncthreads();
    if (ok) {
        float acc = msg_b[o];
#pragma unroll
        for (int d = 0; d < D; ++d)
            acc += ms[ni][d] * msg_w[d * D + o] + xs[ni][d] * msg_w[(D + d) * D + o];
        if (LAST) acc += nf[n * D + o];
        out_new[n * D + o] = acc;
    }
}

extern "C" void kernel_launch(void* const* d_in, const int* in_sizes, int n_in,
                              void* d_out, int out_size, void* d_ws, size_t ws_size,
                              hipStream_t stream) {
    const float* n_feat = (const float*)d_in[0];
    const float* e_feat = (const float*)d_in[1];
    const int* src = (const int*)d_in[2];
    const int* dst = (const int*)d_in[3];
    const float* lin0_w = (const float*)d_in[4];
    const float* lin0_b = (const float*)d_in[5];
    const float* msg_w = (const float*)d_in[6];
    const float* msg_b = (const float*)d_in[7];
    const float* e1_w = (const float*)d_in[8];
    const float* e1_b = (const float*)d_in[9];
    const float* e2_w = (const float*)d_in[10];
    const float* e2_b = (const float*)d_in[11];
    const float* res_w = (const float*)d_in[12];
    const float* conv_b = (const float*)d_in[13];
    float* outF = (float*)d_out;

    char* p = (char*)d_ws;
    bf16* rF = (bf16*)p;      p += (size_t)NE * DH * 2;   // 25.6 MB
    bf16* BtF = (bf16*)p;     p += (size_t)DD * DH * 2;   // 0.41 MB
    float* biasP = (float*)p; p += (size_t)DD * 4;        // 6.4 KB
    float* outA = (float*)p;  p += (size_t)NN * D * 4;    // 8 MB
    float* outB = (float*)p;  p += (size_t)NN * D * 4;    // 8 MB
    float* agg = (float*)p;   p += (size_t)NN * D * 4;    // 8 MB

    k_edge1<<<(NE * 16) / 256, 256, 0, stream>>>(e_feat, e1_w, e1_b, rF);
    k_cvtB<<<(100 * 4 * 64) / 256, 256, 0, stream>>>(e2_w, BtF);
    k_cvtBias<<<(DD + 255) / 256, 256, 0, stream>>>(e2_b, biasP);
    k_lin0<<<(NN * D + 255) / 256, 256, 0, stream>>>(n_feat, lin0_w, lin0_b, outA);

    float* cur = outA;
    float* nxt = outB;
    for (int s = 0; s < 6; ++s) {
        k_zero<<<(NN * D + 255) / 256, 256, 0, stream>>>(agg, NN * D);
        k_msgF3<<<(NEG + 7) / 8, 256, 0, stream>>>(cur, BtF, biasP, rF, src, dst, agg);
        if (s == 5) {
            k_node<1><<<(NN + 5) / 6, 256, 0, stream>>>(cur, agg, res_w, conv_b,
                                                        msg_w, msg_b, n_feat, outF);
        } else {
            k_node<0><<<(NN + 5) / 6, 256, 0, stream>>>(cur, agg, res_w, conv_b,
                                                        msg_w, msg_b, n_feat, nxt);
            float* t = cur; cur = nxt; nxt = t;
        }
    }
}

// Round 15
// 901.307 us; speedup vs baseline: 2.3888x; 1.9789x over previous
//
#include <hip/hip_runtime.h>
#include <hip/hip_bf16.h>

#define NN 50000
#define NE 100000
#define D 40
#define DE 10
#define DH 128
#define DD 1600   // D*D
#define NEG 6250  // NE/16 edge-groups

typedef __bf16 bf16;
typedef bf16 bf16x8 __attribute__((ext_vector_type(8)));
typedef float f32x4 __attribute__((ext_vector_type(4)));

// Fragment-major layouts (one 16-B chunk per lane, contiguous per wave-load):
//   rF  idx = ((eg*4 + s)*64 + lane)*8 + j  holds r[e=eg*16+(lane&15)][k=(lane>>4)*8+s*32+j]
//   BtF idx = ((nt*4 + s)*64 + lane)*8 + j  holds e2_w[k][d*40+o], j'=nt*16+(lane&15), o=j'/40, d=j'%40

__global__ __launch_bounds__(256) void k_zero(float* __restrict__ p, int n) {
    int t = blockIdx.x * 256 + threadIdx.x;
    if (t < n) p[t] = 0.f;
}

// r (fragment-major) = relu(e_feat @ e1_w + e1_b)
__global__ __launch_bounds__(256) void k_edge1(const float* __restrict__ ef,
                                               const float* __restrict__ w,
                                               const float* __restrict__ b,
                                               bf16* __restrict__ rF) {
    int t = blockIdx.x * 256 + threadIdx.x;  // NE*16 threads exact
    int lane = t & 63;
    int e = (t >> 8) * 16 + (lane & 15);
    int kbase = (lane >> 4) * 8 + ((t >> 6) & 3) * 32;
    float efr[DE];
#pragma unroll
    for (int d = 0; d < DE; ++d) efr[d] = ef[e * DE + d];
    bf16x8 ov;
#pragma unroll
    for (int j = 0; j < 8; ++j) {
        int h = kbase + j;
        float acc = b[h];
#pragma unroll
        for (int d = 0; d < DE; ++d) acc += efr[d] * w[d * DH + h];
        ov[j] = (bf16)fmaxf(acc, 0.f);
    }
    *(bf16x8*)(rF + (size_t)t * 8) = ov;
}

// BtF fragment-major from e2_w (one-time, tiny)
__global__ __launch_bounds__(256) void k_cvtB(const float* __restrict__ w,
                                              bf16* __restrict__ btf) {
    int t = blockIdx.x * 256 + threadIdx.x;  // 100*4*64 = 25600 threads exact
    int lane = t & 63;
    int jp = (t >> 8) * 16 + (lane & 15);
    int kbase = (lane >> 4) * 8 + ((t >> 6) & 3) * 32;
    int o = jp / D, d = jp % D;
    bf16x8 ov;
#pragma unroll
    for (int j = 0; j < 8; ++j) ov[j] = (bf16)w[(kbase + j) * DD + d * D + o];
    *(bf16x8*)(btf + (size_t)t * 8) = ov;
}

// biasP[j'] = e2_b[d*40+o]
__global__ __launch_bounds__(256) void k_cvtBias(const float* __restrict__ b,
                                                 float* __restrict__ bp) {
    int t = blockIdx.x * 256 + threadIdx.x;
    if (t >= DD) return;
    int o = t / D, d = t % D;
    bp[t] = b[d * D + o];
}

// out0 = relu(n_feat @ lin0_w + lin0_b)
__global__ __launch_bounds__(256) void k_lin0(const float* __restrict__ nf,
                                              const float* __restrict__ w,
                                              const float* __restrict__ b,
                                              float* __restrict__ out) {
    int t = blockIdx.x * 256 + threadIdx.x;
    if (t >= NN * D) return;
    int o = t % D, n = t / D;
    float acc = b[o];
    const float* x = nf + n * D;
#pragma unroll
    for (int d = 0; d < D; ++d) acc += x[d] * w[d * D + o];
    out[t] = fmaxf(acc, 0.f);
}

// Fused message step v4 = v3 compute (register accum, shfl reduce) + R10/R13
// coalesced flush. Per-m results go to LDS via PLAIN stores (each (edge,o)
// written by exactly one lane once; stride-41 rows -> conflict-free), then one
// barrier and a block-wide flush where consecutive tids cover consecutive o of
// the same edge row -> atomics coalesce into ~3 lines/edge (WRITE 125->16 MB).
__global__ __launch_bounds__(256, 4) void k_msgF4(const float* __restrict__ x,
                                                  const bf16* __restrict__ btf,
                                                  const float* __restrict__ biasp,
                                                  const bf16* __restrict__ rF,
                                                  const int* __restrict__ src,
                                                  const int* __restrict__ dst,
                                                  float* __restrict__ agg) {
    __shared__ float mb[8][16][41];  // 21 KB: [group-in-block][edge][o] (padded)
    __shared__ int dd_s[128];
    int tid = threadIdx.x, wave = tid >> 6, lane = tid & 63;
    int r15 = lane & 15, kg = lane >> 4;
    int g0 = blockIdx.x * 8;
    int eg0 = g0 + wave * 2;
    bool act0 = eg0 < NEG;
    bool act1 = (eg0 + 1) < NEG;

    if (tid < 128) {
        int e = g0 * 16 + tid;
        if (e < NE) dd_s[tid] = dst[e];
    }

    if (act0) {  // wave-uniform branch; NO early return (barrier below)
        int eg1 = act1 ? eg0 + 1 : eg0;
        bf16x8 b0[4], b1[4];
#pragma unroll
        for (int s = 0; s < 4; ++s) {
            b0[s] = *(const bf16x8*)(rF + (size_t)((eg0 * 4 + s) * 64 + lane) * 8);
            b1[s] = *(const bf16x8*)(rF + (size_t)((eg1 * 4 + s) * 64 + lane) * 8);
        }
        int sv0 = src[eg0 * 16 + r15];
        int sv1 = src[eg1 * 16 + r15];
        f32x4 xq0[5], xq1[5];
#pragma unroll
        for (int i = 0; i < 5; ++i) {
            int v = 16 * i + 4 * kg;
            int d0 = v >= 40 ? v - 40 : v;  // static per (i,kg)
            xq0[i] = *(const f32x4*)(x + (size_t)sv0 * D + d0);
            xq1[i] = *(const f32x4*)(x + (size_t)sv1 * D + d0);
        }
        for (int m = 0; m < 20; ++m) {
            float pe0 = 0.f, po0 = 0.f, pe1 = 0.f, po1 = 0.f;
#pragma unroll
            for (int i = 0; i < 5; ++i) {
                int nt = m * 5 + i;
                bf16x8 af[4];
#pragma unroll
                for (int s = 0; s < 4; ++s)
                    af[s] = *(const bf16x8*)(btf + (size_t)((nt * 4 + s) * 64 + lane) * 8);
                f32x4 bias = *(const f32x4*)(biasp + nt * 16 + kg * 4);
                f32x4 a0 = {0.f, 0.f, 0.f, 0.f}, a1 = {0.f, 0.f, 0.f, 0.f};
#pragma unroll
                for (int s = 0; s < 4; ++s) {
                    a0 = __builtin_amdgcn_mfma_f32_16x16x32_bf16(af[s], b0[s], a0, 0, 0, 0);
                    a1 = __builtin_amdgcn_mfma_f32_16x16x32_bf16(af[s], b1[s], a1, 0, 0, 0);
                }
                f32x4 xv0 = xq0[i], xv1 = xq1[i];
                float p0 = (a0[0] + bias[0]) * xv0[0] + (a0[1] + bias[1]) * xv0[1] +
                           (a0[2] + bias[2]) * xv0[2] + (a0[3] + bias[3]) * xv0[3];
                float p1 = (a1[0] + bias[0]) * xv1[0] + (a1[1] + bias[1]) * xv1[1] +
                           (a1[2] + bias[2]) * xv1[2] + (a1[3] + bias[3]) * xv1[3];
                if (i <= 1) { pe0 += p0; pe1 += p1; }       // 16i+4kg < 40 always
                else if (i >= 3) { po0 += p0; po1 += p1; }  // >= 40 always
                else {                                       // i==2: kg>=2 -> hi
                    bool hi = kg >= 2;
                    pe0 += hi ? 0.f : p0; po0 += hi ? p0 : 0.f;
                    pe1 += hi ? 0.f : p1; po1 += hi ? p1 : 0.f;
                }
            }
            // reduce partials across the 4 kg-lanes sharing r15
            pe0 += __shfl_xor(pe0, 16, 64); pe0 += __shfl_xor(pe0, 32, 64);
            po0 += __shfl_xor(po0, 16, 64); po0 += __shfl_xor(po0, 32, 64);
            pe1 += __shfl_xor(pe1, 16, 64); pe1 += __shfl_xor(pe1, 32, 64);
            po1 += __shfl_xor(po1, 16, 64); po1 += __shfl_xor(po1, 32, 64);
            if (lane < 16) {  // plain stores: unique (group, r15, o) per lane
                mb[wave * 2][r15][2 * m] = pe0;
                mb[wave * 2][r15][2 * m + 1] = po0;
                mb[wave * 2 + 1][r15][2 * m] = pe1;
                mb[wave * 2 + 1][r15][2 * m + 1] = po1;
            }
        }
    }
    __syncthreads();
    // coalesced flush: consecutive tid -> consecutive o of same edge row
    for (int idx = tid; idx < 8 * 16 * D; idx += 256) {
        int gl = idx / (16 * D), rem = idx % (16 * D);
        int e_l = rem / D, o = rem % D;
        if (g0 + gl < NEG)
            atomicAdd(&agg[(size_t)dd_s[gl * 16 + e_l] * D + o], mb[gl][e_l][o]);
    }
}

// node update: m = relu(agg + out@res_w + conv_b); out' = [m,out]@msg_w + msg_b (+ n_feat if LAST)
template <int LAST>
__global__ __launch_bounds__(256) void k_node(const float* __restrict__ out,
                                              const float* __restrict__ agg,
                                              const float* __restrict__ res_w,
                                              const float* __restrict__ conv_b,
                                              const float* __restrict__ msg_w,
                                              const float* __restrict__ msg_b,
                                              const float* __restrict__ nf,
                                              float* __restrict__ out_new) {
    __shared__ float xs[6][D], ms[6][D];
    int ni = threadIdx.x / D, o = threadIdx.x % D;
    int n = blockIdx.x * 6 + ni;
    bool ok = (ni < 6) && (n < NN);
    if (ok) xs[ni][o] = out[n * D + o];
    __syncthreads();
    if (ok) {
        float t = conv_b[o] + agg[n * D + o];
#pragma unroll
        for (int d = 0; d < D; ++d) t += xs[ni][d] * res_w[d * D + o];
        ms[ni][o] = fmaxf(t, 0.f);
    }
    __syncthreads();
    if (ok) {
        float acc = msg_b[o];
#pragma unroll
        for (int d = 0; d < D; ++d)
            acc += ms[ni][d] * msg_w[d * D + o] + xs[ni][d] * msg_w[(D + d) * D + o];
        if (LAST) acc += nf[n * D + o];
        out_new[n * D + o] = acc;
    }
}

extern "C" void kernel_launch(void* const* d_in, const int* in_sizes, int n_in,
                              void* d_out, int out_size, void* d_ws, size_t ws_size,
                              hipStream_t stream) {
    const float* n_feat = (const float*)d_in[0];
    const float* e_feat = (const float*)d_in[1];
    const int* src = (const int*)d_in[2];
    const int* dst = (const int*)d_in[3];
    const float* lin0_w = (const float*)d_in[4];
    const float* lin0_b = (const float*)d_in[5];
    const float* msg_w = (const float*)d_in[6];
    const float* msg_b = (const float*)d_in[7];
    const float* e1_w = (const float*)d_in[8];
    const float* e1_b = (const float*)d_in[9];
    const float* e2_w = (const float*)d_in[10];
    const float* e2_b = (const float*)d_in[11];
    const float* res_w = (const float*)d_in[12];
    const float* conv_b = (const float*)d_in[13];
    float* outF = (float*)d_out;

    char* p = (char*)d_ws;
    bf16* rF = (bf16*)p;      p += (size_t)NE * DH * 2;   // 25.6 MB
    bf16* BtF = (bf16*)p;     p += (size_t)DD * DH * 2;   // 0.41 MB
    float* biasP = (float*)p; p += (size_t)DD * 4;        // 6.4 KB
    float* outA = (float*)p;  p += (size_t)NN * D * 4;    // 8 MB
    float* outB = (float*)p;  p += (size_t)NN * D * 4;    // 8 MB
    float* agg = (float*)p;   p += (size_t)NN * D * 4;    // 8 MB

    k_edge1<<<(NE * 16) / 256, 256, 0, stream>>>(e_feat, e1_w, e1_b, rF);
    k_cvtB<<<(100 * 4 * 64) / 256, 256, 0, stream>>>(e2_w, BtF);
    k_cvtBias<<<(DD + 255) / 256, 256, 0, stream>>>(e2_b, biasP);
    k_lin0<<<(NN * D + 255) / 256, 256, 0, stream>>>(n_feat, lin0_w, lin0_b, outA);

    float* cur = outA;
    float* nxt = outB;
    for (int s = 0; s < 6; ++s) {
        k_zero<<<(NN * D + 255) / 256, 256, 0, stream>>>(agg, NN * D);
        k_msgF4<<<(NEG + 7) / 8, 256, 0, stream>>>(cur, BtF, biasP, rF, src, dst, agg);
        if (s == 5) {
            k_node<1><<<(NN + 5) / 6, 256, 0, stream>>>(cur, agg, res_w, conv_b,
                                                        msg_w, msg_b, n_feat, outF);
        } else {
            k_node<0><<<(NN + 5) / 6, 256, 0, stream>>>(cur, agg, res_w, conv_b,
                                                        msg_w, msg_b, n_feat, nxt);
            float* t = cur; cur = nxt; nxt = t;
        }
    }
}